// Round 3
// baseline (114.591 us; speedup 1.0000x reference)
//
#include <hip/hip_runtime.h>

// Bilinear flow warp via LDS-staged tiles.
// images [32,3,512,512] f32, flows [32,2,512,512] f32 (ch0=dy, ch1=dx).
//
// R2 post-mortem: global-gather versions are stuck at ~4 TB/s effective with
// 1.4-1.7x image over-fetch; neither thread mapping fixed it. Here each block
// stages a haloed 144x48 image tile into LDS (coalesced), gathers from LDS,
// and an XCD-contiguous block swizzle keeps vertical halo reuse in-XCD-L2.
// Flow magnitudes are N(0,1) (max ~5.5 over 16.7M draws) so HALO=8 covers all
// taps; a per-pixel global fallback keeps arbitrary flows exactly correct.

constexpr int BN = 32, C = 3, H = 512, W = 512, HW = H * W;
constexpr int TW = 128, TH = 32, HALO = 8;
constexpr int LW  = TW + 2 * HALO;   // 144 staged cols
constexpr int LH  = TH + 2 * HALO;   // 48 staged rows
constexpr int LWP = LW + 1;          // 145: odd stride -> 17 mod 32 spreads banks
constexpr int TILES = BN * (W / TW) * (H / TH);   // 32*4*16 = 2048

__global__ __launch_bounds__(256) void warp_bilinear_lds(
    const float* __restrict__ images,
    const float* __restrict__ flows,
    float* __restrict__ out)
{
    __shared__ float tile[LH * LWP];             // 27,840 B

    // XCD-contiguous swizzle: XCD r owns tiles [r*256, (r+1)*256) = 4 batches.
    int bid = blockIdx.x;
    int tile_id = (bid & 7) * (TILES / 8) + (bid >> 3);
    int b   = tile_id >> 6;                      // 64 tiles per batch
    int rem = tile_id & 63;
    int ty0 = (rem >> 2) * TH;                   // tile_y: 0..15
    int tx0 = (rem & 3)  * TW;                   // tile_x: 0..3

    int tid = threadIdx.x;
    int xl  = tid & (TW - 1);                    // 0..127
    int ybh = tid >> 7;                          // 0..1 (row-half)
    int xg  = tx0 + xl;

    // ---- load flows, compute channel-independent gather state ----
    float dxv[16], dyv[16];
    int   lidx[16];
    unsigned okm = 0;
    const float* flow_y = flows + (size_t)b * 2 * HW;
    const float* flow_x = flow_y + HW;
#pragma unroll
    for (int k = 0; k < 16; ++k) {
        int yl  = ybh * 16 + k;
        int yg  = ty0 + yl;
        int off = yg * W + xg;
        float fy = flow_y[off];
        float fx = flow_x[off];
        float sx = fminf(fmaxf((float)xg + fx, 0.0f), (float)(W - 1));
        float sy = fminf(fmaxf((float)yg + fy, 0.0f), (float)(H - 1));
        int x0 = min((int)sx, W - 2);            // sx >= 0 so (int) == floor
        int y0 = min((int)sy, H - 2);
        dxv[k] = sx - (float)x0;
        dyv[k] = sy - (float)y0;
        int lx0 = x0 - tx0 + HALO;
        int ly0 = y0 - ty0 + HALO;
        bool ok = (lx0 >= 0) & (lx0 <= LW - 2) & (ly0 >= 0) & (ly0 <= LH - 2);
        okm |= (unsigned)ok << k;
        lidx[k] = ok ? (ly0 * LWP + lx0)         // LDS offset
                     : (y0 * W + x0);            // global fallback offset
    }

    // ---- per channel: stage haloed tile (coalesced) -> gather from LDS ----
    for (int c = 0; c < C; ++c) {
        const float* gimg = images + ((size_t)b * C + c) * HW;
        __syncthreads();                          // previous channel's reads done
        for (int i = tid; i < LH * LW; i += 256) {   // 27 iters exactly
            int ly = i / LW;
            int lx = i - ly * LW;
            int gy = min(max(ty0 - HALO + ly, 0), H - 1);
            int gx = min(max(tx0 - HALO + lx, 0), W - 1);
            tile[ly * LWP + lx] = gimg[gy * W + gx];
        }
        __syncthreads();

        float* outc = out + ((size_t)b * C + c) * HW;
#pragma unroll
        for (int k = 0; k < 16; ++k) {
            float dx = dxv[k], dy = dyv[k];
            float wa = (1.0f - dx) * (1.0f - dy);
            float wb = (1.0f - dx) * dy;
            float wc = dx * (1.0f - dy);
            float wd = dx * dy;
            float Ia, Ib, Ic, Id;
            if ((okm >> k) & 1) {
                int li = lidx[k];
                Ia = tile[li];        Ic = tile[li + 1];        // ds_read2_b32
                Ib = tile[li + LWP];  Id = tile[li + LWP + 1];
            } else {                                            // |flow| > ~7: rare
                int gi = lidx[k];
                Ia = gimg[gi];        Ic = gimg[gi + 1];
                Ib = gimg[gi + W];    Id = gimg[gi + W + 1];
            }
            int yl = ybh * 16 + k;
            outc[(ty0 + yl) * W + xg] = wa * Ia + wb * Ib + wc * Ic + wd * Id;
        }
    }
}

extern "C" void kernel_launch(void* const* d_in, const int* in_sizes, int n_in,
                              void* d_out, int out_size, void* d_ws, size_t ws_size,
                              hipStream_t stream) {
    const float* images = (const float*)d_in[0];
    const float* flows  = (const float*)d_in[1];
    float* out = (float*)d_out;

    dim3 block(256);
    dim3 grid(TILES);                             // 2048 blocks, %8 == 0
    hipLaunchKernelGGL(warp_bilinear_lds, grid, block, 0, stream,
                       images, flows, out);
}

// Round 4
// 55.568 us; speedup vs baseline: 2.0622x; 2.0622x over previous
//
#include <hip/hip_runtime.h>

// Bilinear flow warp, LDS row-tile version.
// images [32,3,512,512] f32, flows [32,2,512,512] f32 (ch0=dy, ch1=dx).
//
// R3 post-mortem: 128x32 LDS tiles hit the traffic floor (FETCH 237->82MB)
// but were latency-bound: 16px/thread state (VGPR=120), div-laden staging,
// 21% occupancy. This version: block = 512 threads = one full-width 512x8
// tile (thread = column, 8 rows). No x-halo; y-halo=6. Staging is 5 unrolled
// float4 row-copies (no div/clamp per element). 8px/thread state -> ~60 VGPR,
// LDS 41.3KB -> 3 blocks/CU = 24 waves (75%). Wave-uniform __all() fast path;
// rare (|flow|>6, P~3e-8/px) global fallback keeps exactness.

constexpr int C = 3, H = 512, W = 512, HW = H * W;
constexpr int TH = 8, HALO = 6;
constexpr int LROWS = TH + 2 * HALO;      // 20 staged rows
constexpr int LWP   = W + 4;              // 516 floats: rows offset 4 banks
constexpr int TILES = 32 * (H / TH);      // 2048 blocks, %8 == 0

__global__ __launch_bounds__(512) void warp_bilinear_rows(
    const float* __restrict__ images,
    const float* __restrict__ flows,
    float* __restrict__ out)
{
    __shared__ float tile[LROWS * LWP];   // 41,280 B

    // XCD-contiguous: XCD r owns tiles [r*256,(r+1)*256) = 4 whole batches.
    int bid = blockIdx.x;
    int tile_id = (bid & 7) * (TILES / 8) + (bid >> 3);
    int b   = tile_id >> 6;               // 64 row-tiles per batch
    int ty0 = (tile_id & 63) * TH;

    int tid = threadIdx.x;                // 0..511 = my column

    // ---- flow load + channel-independent gather state (8 px/thread) ----
    const float* flow_y = flows + (size_t)b * 2 * HW + ty0 * W + tid;
    const float* flow_x = flow_y + HW;

    float dxv[TH], dyv[TH];
    int   li[TH];
    unsigned okm = 0;
#pragma unroll
    for (int k = 0; k < TH; ++k) {
        float fy = flow_y[k * W];
        float fx = flow_x[k * W];
        float sx = fminf(fmaxf((float)tid + fx, 0.0f), (float)(W - 1));
        float sy = fminf(fmaxf((float)(ty0 + k) + fy, 0.0f), (float)(H - 1));
        int x0 = min((int)sx, W - 2);     // sx >= 0 so (int) == floor
        int y0 = min((int)sy, H - 2);
        dxv[k] = sx - (float)x0;
        dyv[k] = sy - (float)y0;
        int ly0 = y0 - (ty0 - HALO);
        bool ok = (ly0 >= 0) & (ly0 <= LROWS - 2);
        okm |= (unsigned)ok << k;
        li[k] = ok ? (ly0 * LWP + x0)     // LDS offset (x needs no halo)
                   : (y0 * W + x0);       // global fallback offset
    }
    bool fast = __all(okm == ((1u << TH) - 1));

    // ---- per channel: coalesced float4 row staging -> LDS gather ----
    for (int c = 0; c < C; ++c) {
        const float* gimg = images + ((size_t)b * C + c) * HW;
        __syncthreads();                  // previous channel's reads done
#pragma unroll
        for (int it = 0; it < LROWS / 4; ++it) {      // 5 iters, 4 rows each
            int r  = it * 4 + (tid >> 7);             // 0..19
            int gy = min(max(ty0 - HALO + r, 0), H - 1);
            int c4 = (tid & 127) * 4;
            float4 v = *reinterpret_cast<const float4*>(gimg + gy * W + c4);
            *reinterpret_cast<float4*>(&tile[r * LWP + c4]) = v;
        }
        __syncthreads();

        float* outc = out + ((size_t)b * C + c) * HW + ty0 * W + tid;
        if (fast) {
#pragma unroll
            for (int k = 0; k < TH; ++k) {
                float dx = dxv[k], dy = dyv[k];
                float wa = (1.0f - dx) * (1.0f - dy);
                float wb = (1.0f - dx) * dy;
                float wc = dx * (1.0f - dy);
                float wd = dx * dy;
                int t = li[k];
                float Ia = tile[t];        float Ic = tile[t + 1];
                float Ib = tile[t + LWP];  float Id = tile[t + LWP + 1];
                outc[k * W] = wa * Ia + wb * Ib + wc * Ic + wd * Id;
            }
        } else {                           // ~0-2 waves per launch
#pragma unroll
            for (int k = 0; k < TH; ++k) {
                float dx = dxv[k], dy = dyv[k];
                float wa = (1.0f - dx) * (1.0f - dy);
                float wb = (1.0f - dx) * dy;
                float wc = dx * (1.0f - dy);
                float wd = dx * dy;
                float Ia, Ib, Ic, Id;
                if ((okm >> k) & 1) {
                    int t = li[k];
                    Ia = tile[t];        Ic = tile[t + 1];
                    Ib = tile[t + LWP];  Id = tile[t + LWP + 1];
                } else {
                    int g = li[k];
                    Ia = gimg[g];        Ic = gimg[g + 1];
                    Ib = gimg[g + W];    Id = gimg[g + W + 1];
                }
                outc[k * W] = wa * Ia + wb * Ib + wc * Ic + wd * Id;
            }
        }
    }
}

extern "C" void kernel_launch(void* const* d_in, const int* in_sizes, int n_in,
                              void* d_out, int out_size, void* d_ws, size_t ws_size,
                              hipStream_t stream) {
    const float* images = (const float*)d_in[0];
    const float* flows  = (const float*)d_in[1];
    float* out = (float*)d_out;

    dim3 block(512);
    dim3 grid(TILES);                     // 2048 blocks
    hipLaunchKernelGGL(warp_bilinear_rows, grid, block, 0, stream,
                       images, flows, out);
}

// Round 5
// 45.315 us; speedup vs baseline: 2.5288x; 1.2263x over previous
//
#include <hip/hip_runtime.h>

// Bilinear flow warp, LDS row-tile version, v2.
// images [32,3,512,512] f32, flows [32,2,512,512] f32 (ch0=dy, ch1=dx).
//
// R4 post-mortem: 55.6us, traffic at floor (FETCH 82MB), but occupancy 39%
// (LDS 41.5KB -> 3 blocks/CU) and bank conflicts UP at 5.8M cycles. The +4
// pad was wrong for this pattern: gather lanes read (random row, col~lane),
// so stride 516 makes bank=(x+4*dy)%32 (jitter-randomized collisions) while
// stride 512 makes bank=x%32 (row cancels -> minimal conflicts), and 512x4B
// rows are the canonical conflict-free float4 staging layout. Unpadded LDS
// = 20*512*4 = 40,960B -> EXACTLY 4 blocks/CU (160KiB) = 32 waves = 100%.
// Nontemporal output stores keep the 100MB output from evicting L3-resident
// inputs.

constexpr int C = 3, H = 512, W = 512, HW = H * W;
constexpr int TH = 8, HALO = 6;
constexpr int LROWS = TH + 2 * HALO;      // 20 staged rows
constexpr int LWP   = W;                  // 512: stride == 0 mod 32 banks
constexpr int TILES = 32 * (H / TH);      // 2048 blocks, %8 == 0

__global__ __launch_bounds__(512) void warp_bilinear_rows(
    const float* __restrict__ images,
    const float* __restrict__ flows,
    float* __restrict__ out)
{
    __shared__ float tile[LROWS * LWP];   // 40,960 B -> 4 blocks/CU exactly

    // XCD-contiguous: XCD r owns tiles [r*256,(r+1)*256) = 4 whole batches.
    int bid = blockIdx.x;
    int tile_id = (bid & 7) * (TILES / 8) + (bid >> 3);
    int b   = tile_id >> 6;               // 64 row-tiles per batch
    int ty0 = (tile_id & 63) * TH;

    int tid = threadIdx.x;                // 0..511 = my column

    // ---- flow load + channel-independent gather state (8 px/thread) ----
    const float* flow_y = flows + (size_t)b * 2 * HW + ty0 * W + tid;
    const float* flow_x = flow_y + HW;

    float dxv[TH], dyv[TH];
    int   li[TH];
    unsigned okm = 0;
#pragma unroll
    for (int k = 0; k < TH; ++k) {
        float fy = flow_y[k * W];
        float fx = flow_x[k * W];
        float sx = fminf(fmaxf((float)tid + fx, 0.0f), (float)(W - 1));
        float sy = fminf(fmaxf((float)(ty0 + k) + fy, 0.0f), (float)(H - 1));
        int x0 = min((int)sx, W - 2);     // sx >= 0 so (int) == floor
        int y0 = min((int)sy, H - 2);
        dxv[k] = sx - (float)x0;
        dyv[k] = sy - (float)y0;
        int ly0 = y0 - (ty0 - HALO);
        bool ok = (ly0 >= 0) & (ly0 <= LROWS - 2);
        okm |= (unsigned)ok << k;
        li[k] = ok ? (ly0 * LWP + x0)     // LDS offset (x needs no halo)
                   : (y0 * W + x0);       // global fallback offset
    }
    bool fast = __all(okm == ((1u << TH) - 1));

    // ---- per channel: coalesced float4 row staging -> LDS gather ----
    for (int c = 0; c < C; ++c) {
        const float* gimg = images + ((size_t)b * C + c) * HW;
        __syncthreads();                  // previous channel's reads done
#pragma unroll
        for (int it = 0; it < LROWS / 4; ++it) {      // 5 iters, 4 rows each
            int r  = it * 4 + (tid >> 7);             // 0..19
            int gy = min(max(ty0 - HALO + r, 0), H - 1);
            int c4 = (tid & 127) * 4;
            float4 v = *reinterpret_cast<const float4*>(gimg + gy * W + c4);
            *reinterpret_cast<float4*>(&tile[r * LWP + c4]) = v;
        }
        __syncthreads();

        float* outc = out + ((size_t)b * C + c) * HW + ty0 * W + tid;
        if (fast) {
#pragma unroll
            for (int k = 0; k < TH; ++k) {
                float dx = dxv[k], dy = dyv[k];
                float wa = (1.0f - dx) * (1.0f - dy);
                float wb = (1.0f - dx) * dy;
                float wc = dx * (1.0f - dy);
                float wd = dx * dy;
                int t = li[k];
                float Ia = tile[t];        float Ic = tile[t + 1];
                float Ib = tile[t + LWP];  float Id = tile[t + LWP + 1];
                __builtin_nontemporal_store(
                    wa * Ia + wb * Ib + wc * Ic + wd * Id, outc + k * W);
            }
        } else {                           // rare: any |dy|>~6 in the strip
#pragma unroll
            for (int k = 0; k < TH; ++k) {
                float dx = dxv[k], dy = dyv[k];
                float wa = (1.0f - dx) * (1.0f - dy);
                float wb = (1.0f - dx) * dy;
                float wc = dx * (1.0f - dy);
                float wd = dx * dy;
                float Ia, Ib, Ic, Id;
                if ((okm >> k) & 1) {
                    int t = li[k];
                    Ia = tile[t];        Ic = tile[t + 1];
                    Ib = tile[t + LWP];  Id = tile[t + LWP + 1];
                } else {
                    int g = li[k];
                    Ia = gimg[g];        Ic = gimg[g + 1];
                    Ib = gimg[g + W];    Id = gimg[g + W + 1];
                }
                __builtin_nontemporal_store(
                    wa * Ia + wb * Ib + wc * Ic + wd * Id, outc + k * W);
            }
        }
    }
}

extern "C" void kernel_launch(void* const* d_in, const int* in_sizes, int n_in,
                              void* d_out, int out_size, void* d_ws, size_t ws_size,
                              hipStream_t stream) {
    const float* images = (const float*)d_in[0];
    const float* flows  = (const float*)d_in[1];
    float* out = (float*)d_out;

    dim3 block(512);
    dim3 grid(TILES);                     // 2048 blocks
    hipLaunchKernelGGL(warp_bilinear_rows, grid, block, 0, stream,
                       images, flows, out);
}

// Round 6
// 44.394 us; speedup vs baseline: 2.5813x; 1.0208x over previous
//
#include <hip/hip_runtime.h>

// Bilinear flow warp, LDS row-tile v3.
// images [32,3,512,512] f32, flows [32,2,512,512] f32 (ch0=dy, ch1=dx).
//
// R5 post-mortem: 45.3us; steady-state HBM is write-only (~100MB) -- inputs
// are L3-resident, so the binding constraint is LDS/VMEM pipe work + barrier
// serialization, not HBM. This round removes two pipe terms:
//  1. HALO 6->4: stage 16 rows per 8 output rows (was 20) = -20% staging.
//     Fallback prob ~1e-5/px, exact via the global slow path.
//  2. Staging via __builtin_amdgcn_global_load_lds(16B): our layout is
//     wave-uniform base + lane*16B exactly, so async direct global->LDS
//     removes all 15 ds_write_b128 per wave and the staging VGPR roundtrip.
// LDS drops to 32,768B (occupancy wave-capped at 4 blocks/CU, not LDS-capped).

constexpr int C = 3, H = 512, W = 512, HW = H * W;
constexpr int TH = 8, HALO = 4;
constexpr int LROWS = TH + 2 * HALO;      // 16 staged rows
constexpr int LWP   = W;                  // 512: stride == 0 mod 32 banks
constexpr int TILES = 32 * (H / TH);      // 2048 blocks, %8 == 0

__global__ __launch_bounds__(512) void warp_bilinear_rows(
    const float* __restrict__ images,
    const float* __restrict__ flows,
    float* __restrict__ out)
{
    __shared__ float tile[LROWS * LWP];   // 32,768 B

    // XCD-contiguous: XCD r owns tiles [r*256,(r+1)*256) = 4 whole batches.
    int bid = blockIdx.x;
    int tile_id = (bid & 7) * (TILES / 8) + (bid >> 3);
    int b   = tile_id >> 6;               // 64 row-tiles per batch
    int ty0 = (tile_id & 63) * TH;

    int tid = threadIdx.x;                // 0..511 = my column

    // ---- flow load + channel-independent gather state (8 px/thread) ----
    const float* flow_y = flows + (size_t)b * 2 * HW + ty0 * W + tid;
    const float* flow_x = flow_y + HW;

    float dxv[TH], dyv[TH];
    int   li[TH];
    unsigned okm = 0;
#pragma unroll
    for (int k = 0; k < TH; ++k) {
        float fy = flow_y[k * W];
        float fx = flow_x[k * W];
        float sx = fminf(fmaxf((float)tid + fx, 0.0f), (float)(W - 1));
        float sy = fminf(fmaxf((float)(ty0 + k) + fy, 0.0f), (float)(H - 1));
        int x0 = min((int)sx, W - 2);     // sx >= 0 so (int) == floor
        int y0 = min((int)sy, H - 2);
        dxv[k] = sx - (float)x0;
        dyv[k] = sy - (float)y0;
        int ly0 = y0 - (ty0 - HALO);
        bool ok = (ly0 >= 0) & (ly0 <= LROWS - 2);
        okm |= (unsigned)ok << k;
        li[k] = ok ? (ly0 * LWP + x0)     // LDS offset (x needs no halo)
                   : (y0 * W + x0);       // global fallback offset
    }
    bool fast = __all(okm == ((1u << TH) - 1));

    // staging addresses (per-thread, channel-invariant):
    //   row r = it*4 + (tid>>7)  (wave-uniform), col = (tid&127)*4
    int srow[LROWS / 4];
    int scol = (tid & 127) * 4;
#pragma unroll
    for (int it = 0; it < LROWS / 4; ++it) {      // 4 iters, 4 rows each
        int r  = it * 4 + (tid >> 7);
        srow[it] = min(max(ty0 - HALO + r, 0), H - 1);
    }

    for (int c = 0; c < C; ++c) {
        const float* gimg = images + ((size_t)b * C + c) * HW;
        __syncthreads();                  // previous channel's reads done
#pragma unroll
        for (int it = 0; it < LROWS / 4; ++it) {
            int r = it * 4 + (tid >> 7);
            // dest: wave-uniform base + lane*16B (matches HW contract);
            // src: per-lane global address. Async 16B direct global->LDS.
            __builtin_amdgcn_global_load_lds(
                (const __attribute__((address_space(1))) void*)(gimg + srow[it] * W + scol),
                (__attribute__((address_space(3))) void*)(&tile[r * LWP + scol]),
                16, 0, 0);
        }
        __syncthreads();                  // drains vmcnt -> tile ready

        float* outc = out + ((size_t)b * C + c) * HW + ty0 * W + tid;
        if (fast) {
#pragma unroll
            for (int k = 0; k < TH; ++k) {
                float dx = dxv[k], dy = dyv[k];
                float wa = (1.0f - dx) * (1.0f - dy);
                float wb = (1.0f - dx) * dy;
                float wc = dx * (1.0f - dy);
                float wd = dx * dy;
                int t = li[k];
                float Ia = tile[t];        float Ic = tile[t + 1];
                float Ib = tile[t + LWP];  float Id = tile[t + LWP + 1];
                __builtin_nontemporal_store(
                    wa * Ia + wb * Ib + wc * Ic + wd * Id, outc + k * W);
            }
        } else {                           // rare: |dy| > ~4 near strip edge
#pragma unroll
            for (int k = 0; k < TH; ++k) {
                float dx = dxv[k], dy = dyv[k];
                float wa = (1.0f - dx) * (1.0f - dy);
                float wb = (1.0f - dx) * dy;
                float wc = dx * (1.0f - dy);
                float wd = dx * dy;
                float Ia, Ib, Ic, Id;
                if ((okm >> k) & 1) {
                    int t = li[k];
                    Ia = tile[t];        Ic = tile[t + 1];
                    Ib = tile[t + LWP];  Id = tile[t + LWP + 1];
                } else {
                    int g = li[k];
                    Ia = gimg[g];        Ic = gimg[g + 1];
                    Ib = gimg[g + W];    Id = gimg[g + W + 1];
                }
                __builtin_nontemporal_store(
                    wa * Ia + wb * Ib + wc * Ic + wd * Id, outc + k * W);
            }
        }
    }
}

extern "C" void kernel_launch(void* const* d_in, const int* in_sizes, int n_in,
                              void* d_out, int out_size, void* d_ws, size_t ws_size,
                              hipStream_t stream) {
    const float* images = (const float*)d_in[0];
    const float* flows  = (const float*)d_in[1];
    float* out = (float*)d_out;

    dim3 block(512);
    dim3 grid(TILES);                     // 2048 blocks
    hipLaunchKernelGGL(warp_bilinear_rows, grid, block, 0, stream,
                       images, flows, out);
}